// Round 8
// baseline (179.855 us; speedup 1.0000x reference)
//
#include <hip/hip_runtime.h>
#include <hip/hip_bf16.h>

// B=4, S=4096, D=1024, H=64.
// qs = LN(x@Wq), ks = LN(x@Wk), vs = x@Wv; out = softmax(qs ks^T/8) @ vs.
//  - No online softmax (LN rows have ||r||=8 -> |score|<=8); exp2 with log2e
//    folded into q's LN scale.
//  - k_attn r8: 128 q/block, 4 waves each owning 32 q x ALL keys of the
//    split -> staging/barriers/epilogue per q halved; no cross-wave O
//    reduce. P stays in registers (S^T C-frag == PV B-operand).
//  - k_proj r8: 256-thr blocks, wave-pair K-split (2 waves/SIMD, was 1);
//    2-way acc reduce via LDS; r6 LN epilogue unchanged.

typedef __bf16 bf16x8 __attribute__((ext_vector_type(8)));
typedef __bf16 bf16x4 __attribute__((ext_vector_type(4)));
typedef short s16x4 __attribute__((ext_vector_type(4)));
typedef float f32x4 __attribute__((ext_vector_type(4)));

#define NROW 16384
#define DD   1024
#define HH   64
#define SS   4096
#define LS   68

#if __has_builtin(__builtin_amdgcn_mfma_f32_16x16x16_bf16)
#define MFMA16(a, b, c) __builtin_amdgcn_mfma_f32_16x16x16_bf16((a), (b), (c), 0, 0, 0)
#define HAVE_MFMA16 1
#elif __has_builtin(__builtin_amdgcn_mfma_f32_16x16x16bf16_1k)
#define MFMA16(a, b, c)                                             \
  __builtin_amdgcn_mfma_f32_16x16x16bf16_1k(                        \
      __builtin_bit_cast(s16x4, (a)), __builtin_bit_cast(s16x4, (b)), (c), 0, 0, 0)
#define HAVE_MFMA16 1
#endif

static __device__ inline unsigned short f2bf_u(float x) {
  __bf16 b = (__bf16)x;
  return __builtin_bit_cast(unsigned short, b);
}
static __device__ inline uint2 pk4f(float a, float b, float c, float d) {
  return make_uint2((unsigned)f2bf_u(a) | ((unsigned)f2bf_u(b) << 16),
                    (unsigned)f2bf_u(c) | ((unsigned)f2bf_u(d) << 16));
}
static __device__ inline bf16x8 ld8(const __bf16* p) {
  bf16x4 lo = *reinterpret_cast<const bf16x4*>(p);
  bf16x4 hi = *reinterpret_cast<const bf16x4*>(p + 4);
  return __builtin_shufflevector(lo, hi, 0, 1, 2, 3, 4, 5, 6, 7);
}

// ---------------------------------------------------------------- kernel 1
__global__ __launch_bounds__(256) void k_transpose_w(
    const float* __restrict__ Wq, const float* __restrict__ Wk,
    const float* __restrict__ Wv, __bf16* __restrict__ WT) {
  int idx = blockIdx.x * 256 + threadIdx.x;   // 0..196607
  int mat = idx >> 16;
  int rem = idx & 65535;                      // k*64 + h (coalesced read)
  int k = rem >> 6, h = rem & 63;
  const float* W = (mat == 0) ? Wq : ((mat == 1) ? Wk : Wv);
  WT[(size_t)(mat * 64 + h) * DD + k] = (__bf16)W[rem];
}

// ---------------------------------------------------------------- kernel 2
// Staged projection GEMM, BK=64, 32 rows/block, 256 thr (4 waves).
// Wave w: rows 16*(w&1)+..., K-half 32*(w>>1). 2-way acc reduce at end;
// LN epilogue (r6-validated) in waves 0,1.
__global__ __launch_bounds__(256, 2) void k_proj(
    const float* __restrict__ X, const __bf16* __restrict__ WT,
    __bf16* __restrict__ qb, __bf16* __restrict__ kbp, __bf16* __restrict__ vT) {
  __shared__ __align__(16) char smem[30464];
  __bf16* Xs = (__bf16*)smem;            // 32 x LS  (4352 B)
  __bf16* Ws = (__bf16*)(smem + 4352);   // 192 x LS (26112 B)
  const int t = threadIdx.x, lane = t & 63, w = t >> 6;
  const int quad = lane >> 4, m = lane & 15;
  const int wl = w & 1;    // row half: rows 16wl..16wl+15
  const int kh = w >> 1;   // K half: cols 32kh..32kh+31 of each stage
  const int Mb = blockIdx.x * 32;

  f32x4 acc[12];
#pragma unroll
  for (int i = 0; i < 12; i++) acc[i] = (f32x4){0.f, 0.f, 0.f, 0.f};

  // staging (fully coalesced, 256 thr):
  //  X: 512 float4 chunks; c = t + 256i (i<2): row=c>>4, col=(c&15)*4
  //  W: 1536 bf16x8 chunks; c = t + 256i (i<6): row=c>>3, col=(c&7)*8
  float4 xr[2];
  bf16x8 wr[6];
#pragma unroll
  for (int i = 0; i < 2; i++) {
    int c = t + i * 256, row = c >> 4, col = (c & 15) * 4;
    xr[i] = *reinterpret_cast<const float4*>(&X[(size_t)(Mb + row) * DD + col]);
  }
#pragma unroll
  for (int i = 0; i < 6; i++) {
    int c = t + i * 256, row = c >> 3, col = (c & 7) * 8;
    wr[i] = *reinterpret_cast<const bf16x8*>(&WT[(size_t)row * DD + col]);
  }

  for (int s = 0; s < 16; s++) {
    if (s) __syncthreads();
#pragma unroll
    for (int i = 0; i < 2; i++) {
      int c = t + i * 256, row = c >> 4, col = (c & 15) * 4;
      *reinterpret_cast<uint2*>(&Xs[row * LS + col]) =
          pk4f(xr[i].x, xr[i].y, xr[i].z, xr[i].w);
    }
#pragma unroll
    for (int i = 0; i < 6; i++) {
      int c = t + i * 256, row = c >> 3, col = (c & 7) * 8;
      uint4 raw = __builtin_bit_cast(uint4, wr[i]);
      __bf16* wd = &Ws[row * LS + col];
      *reinterpret_cast<uint2*>(wd) = make_uint2(raw.x, raw.y);
      *reinterpret_cast<uint2*>(wd + 4) = make_uint2(raw.z, raw.w);
    }
    __syncthreads();
    if (s + 1 < 16) {
      const int ko = (s + 1) * 64;
#pragma unroll
      for (int i = 0; i < 2; i++) {
        int c = t + i * 256, row = c >> 4, col = (c & 15) * 4;
        xr[i] = *reinterpret_cast<const float4*>(
            &X[(size_t)(Mb + row) * DD + ko + col]);
      }
#pragma unroll
      for (int i = 0; i < 6; i++) {
        int c = t + i * 256, row = c >> 3, col = (c & 7) * 8;
        wr[i] = *reinterpret_cast<const bf16x8*>(
            &WT[(size_t)row * DD + ko + col]);
      }
    }
    // compute: this wave's K-half only
    bf16x8 a = ld8(&Xs[(16 * wl + m) * LS + 32 * kh + quad * 8]);
#pragma unroll
    for (int nt = 0; nt < 12; nt++) {
      bf16x8 bfr = ld8(&Ws[(16 * nt + m) * LS + 32 * kh + quad * 8]);
      acc[nt] = __builtin_amdgcn_mfma_f32_16x16x32_bf16(a, bfr, acc[nt], 0, 0, 0);
    }
  }

  // ---- 2-way cross-wave reduce over K-halves (waves 2,3 -> 0,1)
  __syncthreads();
  float* red = (float*)smem;   // (wl*64+lane)*52 + nt*4 ; max 26608 B
  if (kh == 1) {
#pragma unroll
    for (int nt = 0; nt < 12; nt++)
      *reinterpret_cast<f32x4*>(&red[(wl * 64 + lane) * 52 + nt * 4]) = acc[nt];
  }
  __syncthreads();
  if (kh == 1) return;
#pragma unroll
  for (int nt = 0; nt < 12; nt++)
    acc[nt] += *reinterpret_cast<const f32x4*>(&red[(wl * 64 + lane) * 52 + nt * 4]);

  // ---- fused LayerNorm in registers (r6-validated), log2e folded into q
#pragma unroll
  for (int mat = 0; mat < 2; mat++) {
#pragma unroll
    for (int reg = 0; reg < 4; reg++) {
      float s = 0.f, s2 = 0.f;
#pragma unroll
      for (int ntl = 0; ntl < 4; ntl++) {
        float x = acc[mat * 4 + ntl][reg];
        s += x; s2 += x * x;
      }
#pragma unroll
      for (int off = 1; off < 16; off <<= 1) {
        s += __shfl_xor(s, off, 64);
        s2 += __shfl_xor(s2, off, 64);
      }
      float mu = s * (1.0f / 64.0f);
      float var = s2 * (1.0f / 64.0f) - mu * mu;
      float rstd = rsqrtf(var + 1e-5f);
      float scl = (mat == 0) ? 0.125f * 1.44269504f * rstd : rstd;
#pragma unroll
      for (int ntl = 0; ntl < 4; ntl++)
        acc[mat * 4 + ntl][reg] = (acc[mat * 4 + ntl][reg] - mu) * scl;
    }
  }

  const int rowbase = Mb + 16 * wl + quad * 4;
#pragma unroll
  for (int nt = 0; nt < 4; nt++)
#pragma unroll
    for (int reg = 0; reg < 4; reg++) {
      qb[(size_t)(rowbase + reg) * HH + m + 16 * nt] = (__bf16)acc[nt][reg];
      kbp[(size_t)(rowbase + reg) * HH + m + 16 * nt] = (__bf16)acc[4 + nt][reg];
    }
  const int b = Mb >> 12;
  const int s0 = (Mb & 4095) + 16 * wl + quad * 4;
#pragma unroll
  for (int nt = 0; nt < 4; nt++) {
    ushort4 pk = make_ushort4(f2bf_u(acc[8 + nt][0]), f2bf_u(acc[8 + nt][1]),
                              f2bf_u(acc[8 + nt][2]), f2bf_u(acc[8 + nt][3]));
    *reinterpret_cast<ushort4*>(
        &vT[((size_t)(b * 64) + m + 16 * nt) * SS + s0]) = pk;
  }
}

// ---------------------------------------------------------------- kernel 3
// S^T attention, 128 q/block. Wave w owns q rows Mb+32w..+31 (2 ntl tiles)
// x ALL keys of the split (ktl 0..3 per 64-key iter). P in registers; no
// cross-wave reduce. Op stored [sp][q][h] (true h columns).
__global__ __launch_bounds__(256, 4) void k_attn(
    const __bf16* __restrict__ qb, const __bf16* __restrict__ kbp,
    const __bf16* __restrict__ vT, float* __restrict__ Op,
    float* __restrict__ lp, int spbits) {
  __shared__ __align__(16) char smem[17408];
  __bf16* Klds = (__bf16*)smem;              // [64 keys][h], stride LS
  __bf16* Vlds = (__bf16*)(smem + 8704);     // [64 h][key], stride LS
  const int t = threadIdx.x, lane = t & 63, w = t >> 6;
  const int quad = lane >> 4, m = lane & 15;
  const int nsp = 1 << spbits;
  const int qt = blockIdx.x >> spbits, sp = blockIdx.x & (nsp - 1);
  const int KPS = SS >> spbits;
  const int Mb = qt * 128;
  const int b = Mb >> 12;
  const size_t kvbase = (size_t)b * SS * HH;

  // Q fragments (B-operand): [ntl][kk], q-row = Mb + 32w + 16ntl + m
  bf16x8 qf[2][2];
#pragma unroll
  for (int ntl = 0; ntl < 2; ntl++)
#pragma unroll
    for (int kk = 0; kk < 2; kk++)
      qf[ntl][kk] = *reinterpret_cast<const bf16x8*>(
          &qb[(size_t)(Mb + 32 * w + 16 * ntl + m) * HH + 32 * kk + quad * 8]);

  f32x4 O[4][2];   // [ht][ntl]
#pragma unroll
  for (int i = 0; i < 4; i++)
#pragma unroll
    for (int j = 0; j < 2; j++) O[i][j] = (f32x4){0.f, 0.f, 0.f, 0.f};
  float ll[2] = {0.f, 0.f};

  const int c0row = t >> 3, ck0 = (t & 7) * 8;
  const int c1row = c0row + 32;
  const int kb_lo = sp * KPS, kb_hi = kb_lo + KPS;

  uint4 kd0, kd1, vd0, vd1;
  kd0 = *reinterpret_cast<const uint4*>(&kbp[kvbase + (size_t)(kb_lo + c0row) * HH + ck0]);
  kd1 = *reinterpret_cast<const uint4*>(&kbp[kvbase + (size_t)(kb_lo + c1row) * HH + ck0]);
  vd0 = *reinterpret_cast<const uint4*>(&vT[(size_t)(b * 64 + c0row) * SS + kb_lo + ck0]);
  vd1 = *reinterpret_cast<const uint4*>(&vT[(size_t)(b * 64 + c1row) * SS + kb_lo + ck0]);

  for (int kb0 = kb_lo; kb0 < kb_hi; kb0 += 64) {
    {
      __bf16* kp0 = &Klds[c0row * LS + ck0];
      __bf16* kp1 = &Klds[c1row * LS + ck0];
      __bf16* vp0 = &Vlds[c0row * LS + ck0];
      __bf16* vp1 = &Vlds[c1row * LS + ck0];
      *reinterpret_cast<uint2*>(kp0) = make_uint2(kd0.x, kd0.y);
      *reinterpret_cast<uint2*>(kp0 + 4) = make_uint2(kd0.z, kd0.w);
      *reinterpret_cast<uint2*>(kp1) = make_uint2(kd1.x, kd1.y);
      *reinterpret_cast<uint2*>(kp1 + 4) = make_uint2(kd1.z, kd1.w);
      *reinterpret_cast<uint2*>(vp0) = make_uint2(vd0.x, vd0.y);
      *reinterpret_cast<uint2*>(vp0 + 4) = make_uint2(vd0.z, vd0.w);
      *reinterpret_cast<uint2*>(vp1) = make_uint2(vd1.x, vd1.y);
      *reinterpret_cast<uint2*>(vp1 + 4) = make_uint2(vd1.z, vd1.w);
    }
    __syncthreads();
    if (kb0 + 64 < kb_hi) {
      kd0 = *reinterpret_cast<const uint4*>(&kbp[kvbase + (size_t)(kb0 + 64 + c0row) * HH + ck0]);
      kd1 = *reinterpret_cast<const uint4*>(&kbp[kvbase + (size_t)(kb0 + 64 + c1row) * HH + ck0]);
      vd0 = *reinterpret_cast<const uint4*>(&vT[(size_t)(b * 64 + c0row) * SS + kb0 + 64 + ck0]);
      vd1 = *reinterpret_cast<const uint4*>(&vT[(size_t)(b * 64 + c1row) * SS + kb0 + 64 + ck0]);
    }

#pragma unroll
    for (int ktl = 0; ktl < 4; ktl++) {
      // S^T = K Q^T : A = K rows (keys as M), B = Q regs
      bf16x8 kf0 = ld8(&Klds[(ktl * 16 + m) * LS + quad * 8]);
      bf16x8 kf1 = ld8(&Klds[(ktl * 16 + m) * LS + 32 + quad * 8]);
      f32x4 sc[2];
      sc[0] = (f32x4){0.f, 0.f, 0.f, 0.f};
      sc[1] = (f32x4){0.f, 0.f, 0.f, 0.f};
#pragma unroll
      for (int ntl = 0; ntl < 2; ntl++) {
        sc[ntl] = __builtin_amdgcn_mfma_f32_16x16x32_bf16(kf0, qf[ntl][0], sc[ntl], 0, 0, 0);
        sc[ntl] = __builtin_amdgcn_mfma_f32_16x16x32_bf16(kf1, qf[ntl][1], sc[ntl], 0, 0, 0);
      }
      bf16x4 pf[2];
#pragma unroll
      for (int ntl = 0; ntl < 2; ntl++) {
        float p0 = exp2f(sc[ntl][0]), p1 = exp2f(sc[ntl][1]);
        float p2 = exp2f(sc[ntl][2]), p3 = exp2f(sc[ntl][3]);
        ll[ntl] += (p0 + p1) + (p2 + p3);
        pf[ntl][0] = (__bf16)p0; pf[ntl][1] = (__bf16)p1;
        pf[ntl][2] = (__bf16)p2; pf[ntl][3] = (__bf16)p3;
      }
#ifdef HAVE_MFMA16
#pragma unroll
      for (int ht = 0; ht < 4; ht++) {
        bf16x4 vf = *reinterpret_cast<const bf16x4*>(
            &Vlds[(16 * ht + m) * LS + ktl * 16 + quad * 4]);
        O[ht][0] = MFMA16(vf, pf[0], O[ht][0]);
        O[ht][1] = MFMA16(vf, pf[1], O[ht][1]);
      }
#else
#pragma unroll
      for (int ntl = 0; ntl < 2; ntl++) {
        uint2 pd = __builtin_bit_cast(uint2, pf[ntl]);
        int lo_src = 32 * quad + m, hi_src = 32 * quad + 16 + m;
        unsigned b0 = (unsigned)__shfl((int)pd.x, lo_src, 64);
        unsigned b1 = (unsigned)__shfl((int)pd.y, lo_src, 64);
        unsigned b2 = (unsigned)__shfl((int)pd.x, hi_src, 64);
        unsigned b3 = (unsigned)__shfl((int)pd.y, hi_src, 64);
        uint4 bz = (quad < 2) ? make_uint4(b0, b1, b2, b3)
                              : make_uint4(0u, 0u, 0u, 0u);
        bf16x8 bfrag = __builtin_bit_cast(bf16x8, bz);
#pragma unroll
        for (int ht = 0; ht < 4; ht++) {
          bf16x8 vf = ld8(&Vlds[(16 * ht + m) * LS + ktl * 16 + (quad & 1) * 8]);
          O[ht][ntl] =
              __builtin_amdgcn_mfma_f32_16x16x32_bf16(vf, bfrag, O[ht][ntl], 0, 0, 0);
        }
      }
#endif
    }
    __syncthreads();
  }

  // l: reduce over quads (keys quad*4+reg)
#pragma unroll
  for (int ntl = 0; ntl < 2; ntl++) {
    ll[ntl] += __shfl_xor(ll[ntl], 16, 64);
    ll[ntl] += __shfl_xor(ll[ntl], 32, 64);
  }

  // ---- direct epilogue: lane owns q-row; O[ht][ntl] = O^T[16ht+4quad+reg][q]
#pragma unroll
  for (int ntl = 0; ntl < 2; ntl++) {
    const int qg = Mb + 32 * w + 16 * ntl + m;
#pragma unroll
    for (int ht = 0; ht < 4; ht++) {
      f32x4 v = O[ht][ntl];
      *reinterpret_cast<float4*>(
          &Op[((size_t)sp * NROW + qg) * HH + 16 * ht + 4 * quad]) =
          make_float4(v[0], v[1], v[2], v[3]);
    }
    if (quad == 0) lp[sp * NROW + qg] = ll[ntl];
  }
}

// ---------------------------------------------------------------- kernel 4
__global__ __launch_bounds__(256) void k_comb(const float* __restrict__ Op,
                                              const float* __restrict__ lp,
                                              float* __restrict__ out, int nsp) {
  int idx = blockIdx.x * 256 + threadIdx.x;   // < NROW*HH
  int row = idx >> 6;
  float o = 0.f, l = 0.f;
  for (int j = 0; j < nsp; j++) {
    o += Op[(size_t)j * NROW * HH + idx];
    l += lp[j * NROW + row];
  }
  out[idx] = o / l;
}

// ---------------------------------------------------------------- launch
extern "C" void kernel_launch(void* const* d_in, const int* in_sizes, int n_in,
                              void* d_out, int out_size, void* d_ws, size_t ws_size,
                              hipStream_t stream) {
  const float* X  = (const float*)d_in[0];
  const float* Wq = (const float*)d_in[1];
  const float* Wk = (const float*)d_in[2];
  const float* Wv = (const float*)d_in[3];
  float* out = (float*)d_out;
  char* ws = (char*)d_ws;

  __bf16* WT  = (__bf16*)(ws);                          // 384 KB
  __bf16* qb  = (__bf16*)(ws + (size_t)512 * 1024);     // 2 MB
  __bf16* kbp = (__bf16*)(ws + (size_t)2560 * 1024);    // 2 MB
  __bf16* vT  = (__bf16*)(ws + (size_t)4608 * 1024);    // 2 MB
  float*  Op  = (float*)(ws + (size_t)6656 * 1024);     // nsp * 4 MB
  const size_t need8 = (size_t)(6656 + 8 * 4096 + 512) * 1024;
  const int spbits = (ws_size >= need8) ? 3 : 2;
  const int nsp = 1 << spbits;
  float* lp = (float*)(ws + (size_t)(6656 + nsp * 4096) * 1024);

  hipLaunchKernelGGL(k_transpose_w, dim3(768), dim3(256), 0, stream, Wq, Wk, Wv, WT);
  hipLaunchKernelGGL(k_proj, dim3(NROW / 32), dim3(256), 0, stream, X, WT, qb, kbp, vT);
  hipLaunchKernelGGL(k_attn, dim3((NROW / 128) * nsp), dim3(256), 0, stream,
                     qb, kbp, vT, Op, lp, spbits);
  hipLaunchKernelGGL(k_comb, dim3(NROW * HH / 256), dim3(256), 0, stream,
                     Op, lp, out, nsp);
}